// Round 3
// baseline (228.559 us; speedup 1.0000x reference)
//
#include <hip/hip_runtime.h>

#define NMS_NUM_CLASSES 16
#define NMS_N 2048
#define NMS_IOU_TH 0.5f
#define NMS_SCORE_TH 0.05f
#define NMS_MAX_DET 100
#define NMS_MAX_PER_CLASS 100

// ---------------------------------------------------------------------------
// Kernel 1: one block per (image, class).
// Compact class candidates (score > TH), rank-sort desc by (score, orig idx
// asc) via LDS scatter, greedy NMS, emit top-100 kept (score + box) to
// workspace; pad score=-1.
// ---------------------------------------------------------------------------
__global__ __launch_bounds__(256) void nms_per_class_kernel(
    const float* __restrict__ pred,   // [B, N, 6] x1,y1,x2,y2,cls,score
    float* __restrict__ ws_scores,    // [B, 16*100]
    float* __restrict__ ws_boxes)     // [B, 16*100, 4]
{
    const int b = blockIdx.x / NMS_NUM_CLASSES;
    const int c = blockIdx.x % NMS_NUM_CLASSES;
    const float* p = pred + (size_t)b * NMS_N * 6;

    // unsorted candidate arrays (48 KB)
    __shared__ float s_scu[NMS_N];
    __shared__ int   s_ixu[NMS_N];
    __shared__ float s_bxu[NMS_N * 4];
    // sorted candidate arrays (42 KB)
    __shared__ float s_sc[NMS_N];
    __shared__ float s_bx[NMS_N * 4];
    __shared__ unsigned char s_keep[NMS_N];
    __shared__ int s_m;

    if (threadIdx.x == 0) s_m = 0;
    __syncthreads();

    // --- compact candidates of class c with score > TH ---
    const float2* p2 = (const float2*)p;   // row i = p2[3i], p2[3i+1], p2[3i+2]
    for (int i = threadIdx.x; i < NMS_N; i += blockDim.x) {
        float2 v0 = p2[i * 3 + 0];   // x1, y1
        float2 v1 = p2[i * 3 + 1];   // x2, y2
        float2 v2 = p2[i * 3 + 2];   // cls, score
        if ((int)v2.x == c && v2.y > NMS_SCORE_TH) {
            int pos = atomicAdd(&s_m, 1);
            s_scu[pos] = v2.y;
            s_ixu[pos] = i;
            s_bxu[pos * 4 + 0] = v0.x;
            s_bxu[pos * 4 + 1] = v0.y;
            s_bxu[pos * 4 + 2] = v1.x;
            s_bxu[pos * 4 + 3] = v1.y;
        }
    }
    __syncthreads();
    const int M = s_m;

    // --- rank sort: desc score, ties -> lower original index first.
    //     rank is a permutation (strict total order), scatter via LDS. ---
    for (int q = threadIdx.x; q < M; q += blockDim.x) {
        float sq = s_scu[q];
        int   iq = s_ixu[q];
        int rk = 0;
        for (int j = 0; j < M; ++j) {
            float sj = s_scu[j];
            rk += (sj > sq) || (sj == sq && s_ixu[j] < iq);
        }
        s_sc[rk] = sq;
        s_bx[rk * 4 + 0] = s_bxu[q * 4 + 0];
        s_bx[rk * 4 + 1] = s_bxu[q * 4 + 1];
        s_bx[rk * 4 + 2] = s_bxu[q * 4 + 2];
        s_bx[rk * 4 + 3] = s_bxu[q * 4 + 3];
        s_keep[rk] = 1;
    }
    __syncthreads();

    // --- greedy NMS: sequential over i (kept), parallel over j > i ---
    for (int i = 0; i < M; ++i) {
        __syncthreads();
        if (s_keep[i]) {   // block-uniform branch (LDS broadcast)
            float x1 = s_bx[i * 4 + 0], y1 = s_bx[i * 4 + 1];
            float x2 = s_bx[i * 4 + 2], y2 = s_bx[i * 4 + 3];
            float ai = (y2 - y1) * (x2 - x1);
            for (int j = i + 1 + threadIdx.x; j < M; j += blockDim.x) {
                if (!s_keep[j]) continue;
                float bx1 = s_bx[j * 4 + 0], by1 = s_bx[j * 4 + 1];
                float bx2 = s_bx[j * 4 + 2], by2 = s_bx[j * 4 + 3];
                float aj = (by2 - by1) * (bx2 - bx1);
                float ih = fminf(y2, by2) - fmaxf(y1, by1);
                ih = fmaxf(ih, 0.0f);
                float iw = fminf(x2, bx2) - fmaxf(x1, bx1);
                iw = fmaxf(iw, 0.0f);
                float inter = ih * iw;
                float uni = ai + aj - inter;
                float iou = (inter > 0.0f) ? inter / fmaxf(uni, 1e-08f) : 0.0f;
                if (iou > NMS_IOU_TH) s_keep[j] = 0;
            }
        }
    }
    __syncthreads();

    // --- emit top-100 kept in sorted order; pad with -1 ---
    if (threadIdx.x == 0) {
        float* osc = ws_scores + ((size_t)b * NMS_NUM_CLASSES + c) * NMS_MAX_PER_CLASS;
        float* obx = ws_boxes + (((size_t)b * NMS_NUM_CLASSES + c) * NMS_MAX_PER_CLASS) * 4;
        int cnt = 0;
        for (int j = 0; j < M && cnt < NMS_MAX_PER_CLASS; ++j) {
            if (s_keep[j]) {
                osc[cnt] = s_sc[j];
                obx[cnt * 4 + 0] = s_bx[j * 4 + 0];
                obx[cnt * 4 + 1] = s_bx[j * 4 + 1];
                obx[cnt * 4 + 2] = s_bx[j * 4 + 2];
                obx[cnt * 4 + 3] = s_bx[j * 4 + 3];
                cnt++;
            }
        }
        for (; cnt < NMS_MAX_PER_CLASS; ++cnt) osc[cnt] = -1.0f;
    }
}

// ---------------------------------------------------------------------------
// Kernel 2: one block per image. Cross-class top-100 of the 1600 slot scores
// (ties -> lower flat slot index = lower class, matching JAX top_k), scatter
// rows [x1,y1,x2,y2,cls,score], zero invalid rows, write nvalid as float.
// ---------------------------------------------------------------------------
__global__ __launch_bounds__(1024) void nms_topk_kernel(
    const float* __restrict__ ws_scores,   // [B, 1600]
    const float* __restrict__ ws_boxes,    // [B, 1600, 4]
    float* __restrict__ out,               // [B*100*6] rows + [B] nvalid at 2400+
    int B)
{
    const int b = blockIdx.x;
    const int NS = NMS_NUM_CLASSES * NMS_MAX_PER_CLASS;   // 1600
    __shared__ float s_sc[NMS_NUM_CLASSES * NMS_MAX_PER_CLASS];
    __shared__ int s_cnt;
    if (threadIdx.x == 0) s_cnt = 0;

    const float* isc = ws_scores + (size_t)b * NS;
    for (int t = threadIdx.x; t < NS; t += blockDim.x) s_sc[t] = isc[t];

    float* ob = out + (size_t)b * NMS_MAX_DET * 6;
    for (int t = threadIdx.x; t < NMS_MAX_DET * 6; t += blockDim.x) ob[t] = 0.0f;
    __syncthreads();

    int localvalid = 0;
    for (int t = threadIdx.x; t < NS; t += blockDim.x) {
        float s = s_sc[t];
        if (s > NMS_SCORE_TH) {
            localvalid++;
            int rk = 0;
            for (int j = 0; j < NS; ++j) {
                float sj = s_sc[j];
                rk += (sj > s) || (sj == s && j < t);
            }
            if (rk < NMS_MAX_DET) {
                const float* bx = ws_boxes + ((size_t)b * NS + t) * 4;
                float* row = ob + rk * 6;
                row[0] = bx[0];
                row[1] = bx[1];
                row[2] = bx[2];
                row[3] = bx[3];
                row[4] = (float)(t / NMS_MAX_PER_CLASS);
                row[5] = s;
            }
        }
    }
    if (localvalid) atomicAdd(&s_cnt, localvalid);
    __syncthreads();
    if (threadIdx.x == 0) {
        int nv = s_cnt;
        if (nv > NMS_MAX_DET) nv = NMS_MAX_DET;
        out[(size_t)B * NMS_MAX_DET * 6 + b] = (float)nv;
    }
}

extern "C" void kernel_launch(void* const* d_in, const int* in_sizes, int n_in,
                              void* d_out, int out_size, void* d_ws, size_t ws_size,
                              hipStream_t stream) {
    const float* pred = (const float*)d_in[0];
    const int B = in_sizes[0] / (NMS_N * 6);
    if (B <= 0) return;
    float* out = (float*)d_out;

    // workspace layout: scores [B*1600] then boxes [B*1600*4]
    float* ws_scores = (float*)d_ws;
    float* ws_boxes = ws_scores + (size_t)B * NMS_NUM_CLASSES * NMS_MAX_PER_CLASS;

    nms_per_class_kernel<<<dim3(B * NMS_NUM_CLASSES), dim3(256), 0, stream>>>(
        pred, ws_scores, ws_boxes);
    nms_topk_kernel<<<dim3(B), dim3(1024), 0, stream>>>(
        ws_scores, ws_boxes, out, B);
}

// Round 4
// 156.922 us; speedup vs baseline: 1.4565x; 1.4565x over previous
//
#include <hip/hip_runtime.h>

#define NMS_NUM_CLASSES 16
#define NMS_N 2048
#define NMS_IOU_TH 0.5f
#define NMS_SCORE_TH 0.05f
#define NMS_MAX_DET 100
#define NMS_MAX_PER_CLASS 100
#define NMS_NS (NMS_NUM_CLASSES * NMS_MAX_PER_CLASS)   // 1600

// ---------------------------------------------------------------------------
// Kernel 1: one block per (image, class).
// (c==0 blocks also zero-init this image's output rows + nvalid slot, since
//  kernel 2 now scatters from many blocks and the harness poisons d_out.)
// Compact class candidates (score > TH), rank-sort desc by (score, orig idx
// asc) via LDS scatter, greedy NMS, emit top-100 kept via block scan; pad
// score=-1.
// ---------------------------------------------------------------------------
__global__ __launch_bounds__(256) void nms_per_class_kernel(
    const float* __restrict__ pred,   // [B, N, 6] x1,y1,x2,y2,cls,score
    float* __restrict__ ws_scores,    // [B, 1600]
    float* __restrict__ ws_boxes,     // [B, 1600, 4]
    float* __restrict__ out,          // [B*600] rows + [B] nvalid
    int B)
{
    const int b = blockIdx.x / NMS_NUM_CLASSES;
    const int c = blockIdx.x % NMS_NUM_CLASSES;
    const float* p = pred + (size_t)b * NMS_N * 6;

    // zero-init output for this image (blocks with c==0 only; k2 is a later
    // dispatch on the same stream, so ordering is guaranteed)
    if (c == 0) {
        float* ob = out + (size_t)b * NMS_MAX_DET * 6;
        for (int t = threadIdx.x; t < NMS_MAX_DET * 6; t += blockDim.x) ob[t] = 0.0f;
        if (threadIdx.x == 0) out[(size_t)B * NMS_MAX_DET * 6 + b] = 0.0f;
    }

    // unsorted candidate arrays
    __shared__ float s_scu[NMS_N];
    __shared__ int   s_ixu[NMS_N];
    __shared__ float s_bxu[NMS_N * 4];
    // sorted candidate arrays
    __shared__ float s_sc[NMS_N];
    __shared__ float s_bx[NMS_N * 4];
    __shared__ unsigned char s_keep[NMS_N];
    __shared__ int s_m;
    __shared__ int s_part[256];
    __shared__ int s_total;

    if (threadIdx.x == 0) s_m = 0;
    __syncthreads();

    // --- compact candidates of class c with score > TH ---
    const float2* p2 = (const float2*)p;   // row i = p2[3i], p2[3i+1], p2[3i+2]
    for (int i = threadIdx.x; i < NMS_N; i += blockDim.x) {
        float2 v0 = p2[i * 3 + 0];   // x1, y1
        float2 v1 = p2[i * 3 + 1];   // x2, y2
        float2 v2 = p2[i * 3 + 2];   // cls, score
        if ((int)v2.x == c && v2.y > NMS_SCORE_TH) {
            int pos = atomicAdd(&s_m, 1);
            s_scu[pos] = v2.y;
            s_ixu[pos] = i;
            s_bxu[pos * 4 + 0] = v0.x;
            s_bxu[pos * 4 + 1] = v0.y;
            s_bxu[pos * 4 + 2] = v1.x;
            s_bxu[pos * 4 + 3] = v1.y;
        }
    }
    __syncthreads();
    const int M = s_m;

    // --- rank sort: desc score, ties -> lower original index first ---
    for (int q = threadIdx.x; q < M; q += blockDim.x) {
        float sq = s_scu[q];
        int   iq = s_ixu[q];
        int rk = 0;
        for (int j = 0; j < M; ++j) {
            float sj = s_scu[j];
            rk += (sj > sq) || (sj == sq && s_ixu[j] < iq);
        }
        s_sc[rk] = sq;
        s_bx[rk * 4 + 0] = s_bxu[q * 4 + 0];
        s_bx[rk * 4 + 1] = s_bxu[q * 4 + 1];
        s_bx[rk * 4 + 2] = s_bxu[q * 4 + 2];
        s_bx[rk * 4 + 3] = s_bxu[q * 4 + 3];
        s_keep[rk] = 1;
    }
    __syncthreads();

    // --- greedy NMS: sequential over i (kept), parallel over j > i ---
    for (int i = 0; i < M; ++i) {
        __syncthreads();
        if (s_keep[i]) {   // block-uniform branch (LDS broadcast)
            float x1 = s_bx[i * 4 + 0], y1 = s_bx[i * 4 + 1];
            float x2 = s_bx[i * 4 + 2], y2 = s_bx[i * 4 + 3];
            float ai = (y2 - y1) * (x2 - x1);
            for (int j = i + 1 + threadIdx.x; j < M; j += blockDim.x) {
                if (!s_keep[j]) continue;
                float bx1 = s_bx[j * 4 + 0], by1 = s_bx[j * 4 + 1];
                float bx2 = s_bx[j * 4 + 2], by2 = s_bx[j * 4 + 3];
                float aj = (by2 - by1) * (bx2 - bx1);
                float ih = fminf(y2, by2) - fmaxf(y1, by1);
                ih = fmaxf(ih, 0.0f);
                float iw = fminf(x2, bx2) - fmaxf(x1, bx1);
                iw = fmaxf(iw, 0.0f);
                float inter = ih * iw;
                float uni = ai + aj - inter;
                float iou = (inter > 0.0f) ? inter / fmaxf(uni, 1e-08f) : 0.0f;
                if (iou > NMS_IOU_TH) s_keep[j] = 0;
            }
        }
    }
    __syncthreads();

    // --- emit top-100 kept in sorted order via block scan; pad with -1 ---
    const int chunk = (M + 255) / 256;           // contiguous slots per thread
    const int lo = threadIdx.x * chunk;
    const int hi = (lo + chunk < M) ? (lo + chunk) : M;
    int cnt = 0;
    for (int j = lo; j < hi; ++j) cnt += s_keep[j];
    s_part[threadIdx.x] = cnt;
    __syncthreads();
    if (threadIdx.x == 0) {
        int acc = 0;
        for (int k = 0; k < 256; ++k) { int v = s_part[k]; s_part[k] = acc; acc += v; }
        s_total = acc;
    }
    __syncthreads();

    float* osc = ws_scores + ((size_t)b * NMS_NUM_CLASSES + c) * NMS_MAX_PER_CLASS;
    float* obx = ws_boxes + (((size_t)b * NMS_NUM_CLASSES + c) * NMS_MAX_PER_CLASS) * 4;
    int pos = s_part[threadIdx.x];
    for (int j = lo; j < hi; ++j) {
        if (s_keep[j]) {
            if (pos < NMS_MAX_PER_CLASS) {
                osc[pos] = s_sc[j];
                obx[pos * 4 + 0] = s_bx[j * 4 + 0];
                obx[pos * 4 + 1] = s_bx[j * 4 + 1];
                obx[pos * 4 + 2] = s_bx[j * 4 + 2];
                obx[pos * 4 + 3] = s_bx[j * 4 + 3];
            }
            pos++;
        }
    }
    // pad positions [total, 100) with -1
    if (threadIdx.x < NMS_MAX_PER_CLASS && threadIdx.x >= s_total)
        osc[threadIdx.x] = -1.0f;
}

// ---------------------------------------------------------------------------
// Kernel 2: one block per (image, class). Each block caches the image's 1600
// slot scores in LDS; thread t<100 computes the global rank of its slot
// (ties -> lower flat slot index, matching JAX top_k) and scatters its row
// into d_out if rank < 100. nvalid accumulated via ballot + atomicAdd:
// count of (valid && rk<100) over all slots == min(#valid, 100).
// ---------------------------------------------------------------------------
__global__ __launch_bounds__(128) void nms_topk_kernel(
    const float* __restrict__ ws_scores,   // [B, 1600]
    const float* __restrict__ ws_boxes,    // [B, 1600, 4]
    float* __restrict__ out,               // [B*600] rows + [B] nvalid
    int B)
{
    const int b = blockIdx.x / NMS_NUM_CLASSES;
    const int c = blockIdx.x % NMS_NUM_CLASSES;
    __shared__ float s_sc[NMS_NS];

    const float* isc = ws_scores + (size_t)b * NMS_NS;
    for (int t = threadIdx.x; t < NMS_NS; t += blockDim.x) s_sc[t] = isc[t];
    __syncthreads();

    int is_top = 0;
    const int t = threadIdx.x;
    if (t < NMS_MAX_PER_CLASS) {
        const int slot = c * NMS_MAX_PER_CLASS + t;
        float s = s_sc[slot];
        if (s > NMS_SCORE_TH) {
            int rk = 0;
            for (int j = 0; j < NMS_NS; ++j) {
                float sj = s_sc[j];
                rk += (sj > s) || (sj == s && j < slot);
            }
            if (rk < NMS_MAX_DET) {
                const float* bx = ws_boxes + ((size_t)b * NMS_NS + slot) * 4;
                float* row = out + (size_t)b * NMS_MAX_DET * 6 + rk * 6;
                row[0] = bx[0];
                row[1] = bx[1];
                row[2] = bx[2];
                row[3] = bx[3];
                row[4] = (float)c;
                row[5] = s;
                is_top = 1;
            }
        }
    }
    unsigned long long m = __ballot(is_top);
    if ((threadIdx.x & 63) == 0) {
        float cnt = (float)__popcll(m);
        if (cnt > 0.0f)
            atomicAdd(&out[(size_t)B * NMS_MAX_DET * 6 + b], cnt);
    }
}

extern "C" void kernel_launch(void* const* d_in, const int* in_sizes, int n_in,
                              void* d_out, int out_size, void* d_ws, size_t ws_size,
                              hipStream_t stream) {
    const float* pred = (const float*)d_in[0];
    const int B = in_sizes[0] / (NMS_N * 6);
    if (B <= 0) return;
    float* out = (float*)d_out;

    // workspace layout: scores [B*1600] then boxes [B*1600*4]
    float* ws_scores = (float*)d_ws;
    float* ws_boxes = ws_scores + (size_t)B * NMS_NS;

    nms_per_class_kernel<<<dim3(B * NMS_NUM_CLASSES), dim3(256), 0, stream>>>(
        pred, ws_scores, ws_boxes, out, B);
    nms_topk_kernel<<<dim3(B * NMS_NUM_CLASSES), dim3(128), 0, stream>>>(
        ws_scores, ws_boxes, out, B);
}